// Round 9
// baseline (94.139 us; speedup 1.0000x reference)
//
#include <hip/hip_runtime.h>

// Problem constants (from reference): B=256, IN=1024, OUT=1024, fp32.
#define BB   256
#define IN_  1024
#define OUTN 1024

// Geometry (round-14): single-shot K staging + persistent blocks.
//   - LDS: 16 x-rows + 16 w-rows x 1024 floats = 128 KiB EXACTLY (m201
//     precedent for 128 KiB static on gfx950). No pad; bank conflicts
//     avoided by XOR swizzle: granule g (16B unit) of row r stored at
//     g ^ (r&7). Read bank-class = (h ^ (r&7)): 8 classes x 2 rows =
//     2-way alias (free, m136) -- same freedom as the proven PAD=4.
//   - Grid 256 blocks x 1024 threads, 1 block/CU (LDS-limited), each
//     block PERSISTENT over 4 output tiles: tile(r) = r*256 + blockIdx;
//     ot = bid&63 is ROUND-INVARIANT -> w staged ONCE; only x (64 KB)
//     re-staged per round, from registers prefetched a full compute
//     phase ahead.
//   - K-loop is barrier-free (single staged buffer covers all of K);
//     4 cheap barriers/round for scratch/restage vs r13's 9 per-stage
//     drain+convergence barriers + 4 ds_read latency ramps.
//
// Why: 8 rounds established an invariant 41.5-44 us across occupancy x2,
// LDS traffic /2, HBM +14MB, packed/scalar/poly op mixes. Issue-demand
// model: 4096 wave-elems/SIMD x (16 cyc trans + ~3 full-rate) + staging
// ~ 82k cyc = 34 us; measured ~100k. The unexplained ~17k is the stage
// machinery -- the only thing never attacked. This round removes it.
// Inner arithmetic is round-13's PASSING v2f code verbatim.
#define TB  16
#define TO  16
#define NR  4            // persistent rounds (output tiles per block)

#define LOG2E 1.4426950408889634f

typedef float v2f __attribute__((ext_vector_type(2)));
typedef float v4f __attribute__((ext_vector_type(4)));

// leaky_clamp(v,0,1,0.1) == med3(v, 0.1*v, 0.9 + 0.1*v). Proven r0-r13.
__device__ __forceinline__ float leaky_clamp01(float v) {
    return __builtin_amdgcn_fmed3f(v, 0.1f * v, fmaf(0.1f, v, 0.9f));
}

// Swizzled float-index of 16B-granule g (0..255) in row r of a [16][1024]
// float array. XOR on g's low 3 bits is bijective per row; write and read
// use the same mapping.
__device__ __forceinline__ int swz(int r, int g) {
    return r * 1024 + ((g ^ (r & 7)) << 2);
}

// Numerics (proven r0-r13): |tau*z| <= ~0.9, so no max-subtraction pass:
// d=sum(2^t), n=sum(2^t * t) with t=(tau*log2e*x)*aw; s = n/(d*tau*log2e).
// The 16-way K-split only repartitions the all-positive-d sums.
__global__ __launch_bounds__(1024, 4)
void esm_fused_kernel(const float* __restrict__ x,
                      const float* __restrict__ w,
                      const float* __restrict__ log_tau,
                      float* __restrict__ out) {
    __shared__ float xs[TB * 1024];    // 64 KiB, swizzled rows
    __shared__ float wls[TO * 1024];   // 64 KiB, swizzled rows

    const int tid = threadIdx.x;       // 0..1023
    const int p   = blockIdx.x;        // 0..255
    const int ot  = p & 63;            // o-tile: fixed across rounds
    const int btb = p >> 6;            // b-tile base; round r: bt = 4r+btb
    const int o0  = ot * TO;

    const float scale = __expf(log_tau[0]) * LOG2E;  // tau * log2(e)

    // h = tid>>6 = wave id = K-16th: thread reads i in {64m+4h..64m+4h+3},
    // m = 0..15. cell = tid&63 -> (ty,tx) in 8x8 pair-grid; thread owns
    // output cells (2ty+r, 2tx+c), r,c in {0,1} (r9/r13-proven mapping;
    // per-wave lane->address pattern identical to r13).
    const int h    = tid >> 6;         // 0..15 (== wave id)
    const int cell = tid & 63;
    const int tx   = cell & 7;         // o-pair index
    const int ty   = cell >> 3;        // b-pair index

    // Staging decode: slot = tid + t*1024 -> row = slot>>8 (srow+4t),
    // granule = slot&255. 64-lane clusters read 1 KB contiguous global
    // (coalesced); swizzled LDS writes permute within 8-granule groups
    // (bank pattern of consecutive granules preserved -> conflict-free).
    const int srow = tid >> 8;         // 0..3
    const int scol = tid & 255;        // granule

    // ---- one-time staging: w (all rounds) + x (round 0) ----
    float4 rx[4], rw[4];
    #pragma unroll
    for (int t = 0; t < 4; ++t) {
        const int row = srow + 4 * t;
        rw[t] = *(const float4*)&w[(size_t)(o0 + row) * IN_ + (scol << 2)];
        rx[t] = *(const float4*)&x[(size_t)(btb * TB + row) * IN_ + (scol << 2)];
    }
    #pragma unroll
    for (int t = 0; t < 4; ++t) {
        const int row = srow + 4 * t;
        const float4 wv = rw[t];
        float4 wo;
        wo.x = leaky_clamp01(wv.x); wo.y = leaky_clamp01(wv.y);
        wo.z = leaky_clamp01(wv.z); wo.w = leaky_clamp01(wv.w);
        *(float4*)&wls[swz(row, scol)] = wo;
        const float4 xv = rx[t];
        float4 xo;
        xo.x = xv.x * scale; xo.y = xv.y * scale;
        xo.z = xv.z * scale; xo.w = xv.w * scale;
        *(float4*)&xs[swz(row, scol)] = xo;
    }
    __syncthreads();                   // staged data visible

    // Hoisted swizzled row base pointers (per-thread constant): address of
    // granule 16m+h in row r is base_r + 64m floats (m -> ds offset imm).
    // (16m+h)^(r&7) == 16m + (h^(r&7)) since the XOR touches only bits 0-2.
    const float* xr0 = &xs[2 * ty * 1024 + ((h ^ ((2 * ty) & 7)) << 2)];
    const float* xr1 = &xs[(2 * ty + 1) * 1024 + ((h ^ ((2 * ty + 1) & 7)) << 2)];
    const float* wr0 = &wls[2 * tx * 1024 + ((h ^ ((2 * tx) & 7)) << 2)];
    const float* wr1 = &wls[(2 * tx + 1) * 1024 + ((h ^ ((2 * tx + 1) & 7)) << 2)];

    #pragma unroll
    for (int r = 0; r < NR; ++r) {
        const int b0 = (4 * r + btb) * TB;

        // Prefetch next round's x BEFORE compute: loads fly under the
        // full ~16k-cycle compute phase (r9-proven pattern).
        if (r + 1 < NR) {
            const int b0n = (4 * (r + 1) + btb) * TB;
            #pragma unroll
            for (int t = 0; t < 4; ++t)
                rx[t] = *(const float4*)&x[(size_t)(b0n + srow + 4 * t) * IN_ + (scol << 2)];
        }

        // ---- barrier-free K loop over all 1024 i's (16 groups of 64) ----
        v2f d00 = {0.f, 0.f}, d01 = {0.f, 0.f}, d10 = {0.f, 0.f}, d11 = {0.f, 0.f};
        v2f n00 = {0.f, 0.f}, n01 = {0.f, 0.f}, n10 = {0.f, 0.f}, n11 = {0.f, 0.f};
        #pragma unroll 4
        for (int m = 0; m < 16; ++m) {
            const v4f xa0 = *(const v4f*)(xr0 + (m << 6));
            const v4f xa1 = *(const v4f*)(xr1 + (m << 6));
            const v4f wa0 = *(const v4f*)(wr0 + (m << 6));
            const v4f wa1 = *(const v4f*)(wr1 + (m << 6));
            #pragma unroll
            for (int q = 0; q < 2; ++q) {
                const v2f xv0 = {xa0[2 * q], xa0[2 * q + 1]};
                const v2f xv1 = {xa1[2 * q], xa1[2 * q + 1]};
                const v2f wv0 = {wa0[2 * q], wa0[2 * q + 1]};
                const v2f wv1 = {wa1[2 * q], wa1[2 * q + 1]};
                const v2f t00 = xv0 * wv0;
                const v2f t01 = xv0 * wv1;
                const v2f t10 = xv1 * wv0;
                const v2f t11 = xv1 * wv1;
                v2f e00, e01, e10, e11;
                e00.x = __builtin_amdgcn_exp2f(t00.x);
                e00.y = __builtin_amdgcn_exp2f(t00.y);
                e01.x = __builtin_amdgcn_exp2f(t01.x);
                e01.y = __builtin_amdgcn_exp2f(t01.y);
                e10.x = __builtin_amdgcn_exp2f(t10.x);
                e10.y = __builtin_amdgcn_exp2f(t10.y);
                e11.x = __builtin_amdgcn_exp2f(t11.x);
                e11.y = __builtin_amdgcn_exp2f(t11.y);
                d00 += e00; d01 += e01; d10 += e10; d11 += e11;
                n00 = __builtin_elementwise_fma(e00, t00, n00);
                n01 = __builtin_elementwise_fma(e01, t01, n01);
                n10 = __builtin_elementwise_fma(e10, t10, n10);
                n11 = __builtin_elementwise_fma(e11, t11, n11);
            }
        }

        // Per-thread scalar partials for the 4 owned cells.
        const float d00s = d00.x + d00.y, n00s = n00.x + n00.y;
        const float d01s = d01.x + d01.y, n01s = n01.x + n01.y;
        const float d10s = d10.x + d10.y, n10s = n10.x + n10.y;
        const float d11s = d11.x + d11.y, n11s = n11.x + n11.y;

        // 16-way K-reduction through scratch in xs (dead after compute;
        // w stays live in wls). sd = xs[0..4095], sn = xs[4096..8191];
        // every (h, cell) slot written by exactly one thread.
        __syncthreads();               // all xs reads (compute) done
        float* sd = xs;
        float* sn = xs + 4096;
        const int co = 32 * ty + 2 * tx;
        sd[(h << 8) + co]      = d00s;
        sd[(h << 8) + co + 1]  = d01s;
        sd[(h << 8) + co + 16] = d10s;
        sd[(h << 8) + co + 17] = d11s;
        sn[(h << 8) + co]      = n00s;
        sn[(h << 8) + co + 1]  = n01s;
        sn[(h << 8) + co + 16] = n10s;
        sn[(h << 8) + co + 17] = n11s;
        __syncthreads();               // scratch visible
        // Flat-cell parallel finalize: thread c < 256 owns output cell c.
        // Reads stride-256 (bank = c mod 32: conflict-free); stores are
        // 4 x 64B segments per wave.
        if (tid < 256) {
            float dt = 0.f, nt = 0.f;
            #pragma unroll
            for (int hh = 0; hh < 16; ++hh) {
                dt += sd[(hh << 8) + tid];
                nt += sn[(hh << 8) + tid];
            }
            out[(size_t)(b0 + (tid >> 4)) * OUTN + o0 + (tid & 15)] = nt / (dt * scale);
        }

        // Re-stage x for the next round (overwrites xs including scratch).
        if (r + 1 < NR) {
            __syncthreads();           // scratch reads done
            #pragma unroll
            for (int t = 0; t < 4; ++t) {
                const int row = srow + 4 * t;
                const float4 xv = rx[t];
                float4 xo;
                xo.x = xv.x * scale; xo.y = xv.y * scale;
                xo.z = xv.z * scale; xo.w = xv.w * scale;
                *(float4*)&xs[swz(row, scol)] = xo;
            }
            __syncthreads();           // new xs visible
        }
    }
}

extern "C" void kernel_launch(void* const* d_in, const int* in_sizes, int n_in,
                              void* d_out, int out_size, void* d_ws, size_t ws_size,
                              hipStream_t stream) {
    const float* x  = (const float*)d_in[0];   // (256, 1024)
    const float* w  = (const float*)d_in[1];   // (1024, 1024)
    const float* lt = (const float*)d_in[2];   // scalar log_tau
    float* out = (float*)d_out;                // (256, 1024)

    esm_fused_kernel<<<256, 1024, 0, stream>>>(x, w, lt, out);
}